// Round 7
// baseline (194.668 us; speedup 1.0000x reference)
//
#include <hip/hip_runtime.h>

#define BATCH 16
#define TOK   4096
#define DIM   768
#define SMAX  128
#define BM    8     // rows per MLP block
#define BK1   32    // layer1 k-tile
#define NT1   24    // 768/32
#define BK2   64    // layer2 k-tile
#define NT2   6     // 384/64

// LDS float offsets
#define OFF_A   0
#define OFF_X1  6144
#define OFF_X2  9216
#define OFF_WB  10240
#define WB1_STRIDE 12288   // BK1*384
#define WB2_STRIDE 8192    // BK2*128
#define LDS_FLOATS (10240 + 2*12288)

__device__ __forceinline__ int lower_bound_i(const int* __restrict__ a, int n, int v) {
    int lo = 0, hi = n;
    while (lo < hi) {
        int m = (lo + hi) >> 1;
        if (a[m] < v) lo = m + 1; else hi = m;
    }
    return lo;
}

__device__ __forceinline__ float f4get(const float4& v, int k) {
    switch (k) {
        case 0: return v.x;
        case 1: return v.y;
        case 2: return v.z;
        default: return v.w;
    }
}

__device__ __forceinline__ void f4acc(float4& a, const float4& v) {
    a.x += v.x; a.y += v.y; a.z += v.z; a.w += v.w;
}

// Kernel A: per-(b,s) segment sum over contiguous sorted token span.
// (unchanged for attribution)
__global__ __launch_bounds__(192)
void segsum_kernel(const float* __restrict__ hidden,
                   const int* __restrict__ seg,
                   float* __restrict__ sent) {
    const int s = blockIdx.x;
    const int b = blockIdx.y;
    const int tid = threadIdx.x;

    const int* srow = seg + b * TOK;
    const int lo = lower_bound_i(srow, TOK, s);
    const int hi = lower_bound_i(srow, TOK, s + 1);

    const float4* __restrict__ hp =
        reinterpret_cast<const float4*>(hidden + (size_t)b * TOK * DIM) + tid;

    float4 acc = make_float4(0.f, 0.f, 0.f, 0.f);
    int t = lo;

    for (; t + 16 <= hi; t += 16) {
        float4 v[16];
        #pragma unroll
        for (int u = 0; u < 16; ++u)
            v[u] = hp[(size_t)(t + u) * (DIM / 4)];
        #pragma unroll
        for (int u = 0; u < 16; ++u)
            f4acc(acc, v[u]);
    }
    for (; t + 4 <= hi; t += 4) {
        float4 v[4];
        #pragma unroll
        for (int u = 0; u < 4; ++u)
            v[u] = hp[(size_t)(t + u) * (DIM / 4)];
        #pragma unroll
        for (int u = 0; u < 4; ++u)
            f4acc(acc, v[u]);
    }
    for (; t < hi; ++t)
        f4acc(acc, hp[(size_t)t * (DIM / 4)]);

    float4* outp = reinterpret_cast<float4*>(sent + (size_t)(b * SMAX + s) * DIM);
    outp[tid] = acc;
}

// Kernel B: fused MLP, weights double-buffer-staged through LDS.
// 256 threads, BM=8 rows; c1 = tid&127 (col), g = tid>>7 (rows 4g..4g+3).
__global__ __launch_bounds__(256)
void mlp_kernel(const float* __restrict__ sent,
                const float* __restrict__ W1, const float* __restrict__ b1,
                const float* __restrict__ W2, const float* __restrict__ b2,
                const float* __restrict__ W3, const float* __restrict__ b3,
                float* __restrict__ out) {
    extern __shared__ float lds[];
    float* A   = lds + OFF_A;    // [BM][768]
    float* X1s = lds + OFF_X1;   // [BM][384]
    float* X2s = lds + OFF_X2;   // [BM][128]
    float* Wb  = lds + OFF_WB;   // weight staging (2 buffers)

    const int tid = threadIdx.x;
    const int row0 = blockIdx.x * BM;

    // Stage A tile (6 float4/thread) + W1 k-tile 0 (12 float4/thread)
    {
        const float4* sA = reinterpret_cast<const float4*>(sent + (size_t)row0 * DIM);
        float4* dA = reinterpret_cast<float4*>(A);
        #pragma unroll
        for (int i = 0; i < 6; ++i) dA[tid + i * 256] = sA[tid + i * 256];
        const float4* sW = reinterpret_cast<const float4*>(W1);
        float4* dW = reinterpret_cast<float4*>(Wb);
        #pragma unroll
        for (int i = 0; i < 12; ++i) dW[tid + i * 256] = sW[tid + i * 256];
    }
    __syncthreads();

    const int c1 = tid & 127;
    const int g  = tid >> 7;
    const int r0 = g * 4;

    // ---- layer 1: acc[4 rows][3 cols], k tiled by BK1, double-buffered ----
    float acc[4][3];
    #pragma unroll
    for (int i = 0; i < 4; ++i)
        #pragma unroll
        for (int j = 0; j < 3; ++j) acc[i][j] = 0.f;

    for (int kt = 0; kt < NT1; ++kt) {
        // issue next tile's global loads early (held in regs, written late: T14)
        float4 tmp[12];
        const bool pf = (kt + 1 < NT1);
        if (pf) {
            const float4* sW = reinterpret_cast<const float4*>(W1 + (size_t)(kt + 1) * BK1 * 384);
            #pragma unroll
            for (int i = 0; i < 12; ++i) tmp[i] = sW[tid + i * 256];
        }
        const float* wr = Wb + (kt & 1) * WB1_STRIDE;
        const int k0 = kt * BK1;
        for (int k = 0; k < BK1; k += 4) {
            float4 a[4];
            #pragma unroll
            for (int i = 0; i < 4; ++i)
                a[i] = *reinterpret_cast<const float4*>(&A[(r0 + i) * DIM + k0 + k]);
            #pragma unroll
            for (int kk = 0; kk < 4; ++kk) {
                const float w0 = wr[(k + kk) * 384 + c1];
                const float w1 = wr[(k + kk) * 384 + c1 + 128];
                const float w2 = wr[(k + kk) * 384 + c1 + 256];
                #pragma unroll
                for (int i = 0; i < 4; ++i) {
                    const float av = f4get(a[i], kk);
                    acc[i][0] = fmaf(av, w0, acc[i][0]);
                    acc[i][1] = fmaf(av, w1, acc[i][1]);
                    acc[i][2] = fmaf(av, w2, acc[i][2]);
                }
            }
        }
        if (pf) {
            float4* dW = reinterpret_cast<float4*>(Wb + ((kt + 1) & 1) * WB1_STRIDE);
            #pragma unroll
            for (int i = 0; i < 12; ++i) dW[tid + i * 256] = tmp[i];
        }
        __syncthreads();
    }
    #pragma unroll
    for (int j = 0; j < 3; ++j) {
        const float bb = b1[c1 + j * 128];
        #pragma unroll
        for (int i = 0; i < 4; ++i) {
            const float v = acc[i][j] + bb;
            X1s[(r0 + i) * 384 + c1 + j * 128] = v > 0.f ? v : 0.f;
        }
    }
    // stage W2 k-tile 0 (8 float4/thread), then one sync covers X1s too
    {
        const float4* sW = reinterpret_cast<const float4*>(W2);
        float4* dW = reinterpret_cast<float4*>(Wb);
        #pragma unroll
        for (int i = 0; i < 8; ++i) dW[tid + i * 256] = sW[tid + i * 256];
    }
    __syncthreads();

    // ---- layer 2: acc2[4 rows] x col c1, k tiled by BK2, double-buffered ----
    float acc2[4] = {0.f, 0.f, 0.f, 0.f};
    for (int kt = 0; kt < NT2; ++kt) {
        float4 tmp[8];
        const bool pf = (kt + 1 < NT2);
        if (pf) {
            const float4* sW = reinterpret_cast<const float4*>(W2 + (size_t)(kt + 1) * BK2 * 128);
            #pragma unroll
            for (int i = 0; i < 8; ++i) tmp[i] = sW[tid + i * 256];
        }
        const float* wr = Wb + (kt & 1) * WB2_STRIDE;
        const int k0 = kt * BK2;
        for (int k = 0; k < BK2; k += 4) {
            float4 x[4];
            #pragma unroll
            for (int i = 0; i < 4; ++i)
                x[i] = *reinterpret_cast<const float4*>(&X1s[(r0 + i) * 384 + k0 + k]);
            #pragma unroll
            for (int kk = 0; kk < 4; ++kk) {
                const float w = wr[(k + kk) * 128 + c1];
                #pragma unroll
                for (int i = 0; i < 4; ++i)
                    acc2[i] = fmaf(f4get(x[i], kk), w, acc2[i]);
            }
        }
        if (pf) {
            float4* dW = reinterpret_cast<float4*>(Wb + ((kt + 1) & 1) * WB2_STRIDE);
            #pragma unroll
            for (int i = 0; i < 8; ++i) dW[tid + i * 256] = tmp[i];
        }
        __syncthreads();
    }
    {
        const float bb = b2[c1];
        #pragma unroll
        for (int i = 0; i < 4; ++i) {
            const float v = acc2[i] + bb;
            X2s[(r0 + i) * 128 + c1] = v > 0.f ? v : 0.f;
        }
    }
    __syncthreads();

    // ---- layer 3: BM*2 = 16 outputs ----
    if (tid < BM * 2) {
        const int r = tid >> 1;
        const int c = tid & 1;
        float sacc = 0.f;
        #pragma unroll 8
        for (int k = 0; k < 128; ++k)
            sacc = fmaf(X2s[r * 128 + k], W3[k * 2 + c], sacc);
        out[(row0 + r) * 2 + c] = sacc + b3[c];
    }
}

extern "C" void kernel_launch(void* const* d_in, const int* in_sizes, int n_in,
                              void* d_out, int out_size, void* d_ws, size_t ws_size,
                              hipStream_t stream) {
    const float* hidden = (const float*)d_in[0];
    const int*   seg    = (const int*)d_in[1];
    const float* W1     = (const float*)d_in[2];
    const float* b1     = (const float*)d_in[3];
    const float* W2     = (const float*)d_in[4];
    const float* b2     = (const float*)d_in[5];
    const float* W3     = (const float*)d_in[6];
    const float* b3     = (const float*)d_in[7];
    float* out  = (float*)d_out;
    float* sent = (float*)d_ws;  // BATCH*SMAX*DIM floats = 6 MB

    segsum_kernel<<<dim3(SMAX, BATCH), 192, 0, stream>>>(hidden, seg, sent);
    mlp_kernel<<<(BATCH * SMAX) / BM, 256, LDS_FLOATS * sizeof(float), stream>>>(
        sent, W1, b1, W2, b2, W3, b3, out);
}

// Round 8
// 70.128 us; speedup vs baseline: 2.7759x; 2.7759x over previous
//
#include <hip/hip_runtime.h>

#define BATCH 16
#define TOK   4096
#define DIM   768
#define SMAX  128
#define BM    8     // rows per MLP block

__device__ __forceinline__ int lower_bound_i(const int* __restrict__ a, int n, int v) {
    int lo = 0, hi = n;
    while (lo < hi) {
        int m = (lo + hi) >> 1;
        if (a[m] < v) lo = m + 1; else hi = m;
    }
    return lo;
}

__device__ __forceinline__ float f4get(const float4& v, int k) {
    switch (k) {
        case 0: return v.x;
        case 1: return v.y;
        case 2: return v.z;
        default: return v.w;
    }
}

__device__ __forceinline__ void f4acc(float4& a, const float4& v) {
    a.x += v.x; a.y += v.y; a.z += v.z; a.w += v.w;
}

// Kernel A: per-(b,s) segment sum over contiguous sorted token span.
// (unchanged for attribution)
__global__ __launch_bounds__(192)
void segsum_kernel(const float* __restrict__ hidden,
                   const int* __restrict__ seg,
                   float* __restrict__ sent) {
    const int s = blockIdx.x;
    const int b = blockIdx.y;
    const int tid = threadIdx.x;

    const int* srow = seg + b * TOK;
    const int lo = lower_bound_i(srow, TOK, s);
    const int hi = lower_bound_i(srow, TOK, s + 1);

    const float4* __restrict__ hp =
        reinterpret_cast<const float4*>(hidden + (size_t)b * TOK * DIM) + tid;

    float4 acc = make_float4(0.f, 0.f, 0.f, 0.f);
    int t = lo;

    for (; t + 16 <= hi; t += 16) {
        float4 v[16];
        #pragma unroll
        for (int u = 0; u < 16; ++u)
            v[u] = hp[(size_t)(t + u) * (DIM / 4)];
        #pragma unroll
        for (int u = 0; u < 16; ++u)
            f4acc(acc, v[u]);
    }
    for (; t + 4 <= hi; t += 4) {
        float4 v[4];
        #pragma unroll
        for (int u = 0; u < 4; ++u)
            v[u] = hp[(size_t)(t + u) * (DIM / 4)];
        #pragma unroll
        for (int u = 0; u < 4; ++u)
            f4acc(acc, v[u]);
    }
    for (; t < hi; ++t)
        f4acc(acc, hp[(size_t)t * (DIM / 4)]);

    float4* outp = reinterpret_cast<float4*>(sent + (size_t)(b * SMAX + s) * DIM);
    outp[tid] = acc;
}

// Kernel B: fused MLP, BM=8 rows/block, 1024 threads (16 waves = 4/SIMD).
// k-split across 8 wave-pair groups -> weights read exactly once per block,
// partials reduced deterministically through LDS. Weights stream from L2.
__global__ __launch_bounds__(1024, 4)
void mlp_kernel(const float* __restrict__ sent,
                const float* __restrict__ W1, const float* __restrict__ b1,
                const float* __restrict__ W2, const float* __restrict__ b2,
                const float* __restrict__ W3, const float* __restrict__ b3,
                float* __restrict__ out) {
    __shared__ __align__(16) float A [BM * DIM];        // 24 KB
    __shared__ __align__(16) float X1[BM * 384];        // 12 KB
    __shared__ __align__(16) float X2[BM * 128];        //  4 KB
    __shared__ __align__(16) float P [8 * BM * 384];    // 96 KB (P1; reused as P2)

    const int tid  = threadIdx.x;
    const int row0 = blockIdx.x * BM;
    const int c1   = tid & 127;   // weight column within 128-group
    const int kg   = tid >> 7;    // k-slice group 0..7 (uniform per wave)

    // ---- stage A tile: 1536 float4 over 1024 threads ----
    {
        const float4* sA = reinterpret_cast<const float4*>(sent + (size_t)row0 * DIM);
        float4* dA = reinterpret_cast<float4*>(A);
        for (int i = tid; i < BM * DIM / 4; i += 1024)
            dA[i] = sA[i];
    }
    __syncthreads();

    // ---- layer 1: this thread: cols {c1, c1+128, c1+256}, rows 0..7,
    //      k in [kg*96, kg*96+96). Weights straight from global (L2). ----
    {
        float acc[BM][3];
        #pragma unroll
        for (int r = 0; r < BM; ++r)
            #pragma unroll
            for (int j = 0; j < 3; ++j) acc[r][j] = 0.f;

        const int k0 = kg * 96;
        for (int k = k0; k < k0 + 96; k += 4) {
            float4 a[BM];
            #pragma unroll
            for (int r = 0; r < BM; ++r)
                a[r] = *reinterpret_cast<const float4*>(&A[r * DIM + k]);
            #pragma unroll
            for (int kk = 0; kk < 4; ++kk) {
                const float w0 = W1[(size_t)(k + kk) * 384 + c1];
                const float w1 = W1[(size_t)(k + kk) * 384 + c1 + 128];
                const float w2 = W1[(size_t)(k + kk) * 384 + c1 + 256];
                #pragma unroll
                for (int r = 0; r < BM; ++r) {
                    const float av = f4get(a[r], kk);
                    acc[r][0] = fmaf(av, w0, acc[r][0]);
                    acc[r][1] = fmaf(av, w1, acc[r][1]);
                    acc[r][2] = fmaf(av, w2, acc[r][2]);
                }
            }
        }
        #pragma unroll
        for (int r = 0; r < BM; ++r)
            #pragma unroll
            for (int j = 0; j < 3; ++j)
                P[(kg * BM + r) * 384 + c1 + j * 128] = acc[r][j];
    }
    __syncthreads();

    // ---- reduce partials -> X1 (bias + relu), 3072 outputs ----
    for (int i = tid; i < BM * 384; i += 1024) {
        const int row = i / 384;
        const int col = i - row * 384;
        float s = b1[col];
        #pragma unroll
        for (int g = 0; g < 8; ++g)
            s += P[(g * BM + row) * 384 + col];
        X1[i] = s > 0.f ? s : 0.f;
    }
    __syncthreads();

    // ---- layer 2: col c1, rows 0..7, k in [kg*48, kg*48+48) ----
    {
        float acc2[BM];
        #pragma unroll
        for (int r = 0; r < BM; ++r) acc2[r] = 0.f;

        const int k0 = kg * 48;
        for (int k = k0; k < k0 + 48; k += 4) {
            float4 x[BM];
            #pragma unroll
            for (int r = 0; r < BM; ++r)
                x[r] = *reinterpret_cast<const float4*>(&X1[r * 384 + k]);
            #pragma unroll
            for (int kk = 0; kk < 4; ++kk) {
                const float w = W2[(size_t)(k + kk) * 128 + c1];
                #pragma unroll
                for (int r = 0; r < BM; ++r)
                    acc2[r] = fmaf(f4get(x[r], kk), w, acc2[r]);
            }
        }
        #pragma unroll
        for (int r = 0; r < BM; ++r)
            P[(kg * BM + r) * 128 + c1] = acc2[r];
    }
    __syncthreads();

    // ---- reduce partials -> X2 (bias + relu), 1024 outputs ----
    {
        const int row = tid >> 7;   // 0..7
        const int col = c1;
        float s = b2[col];
        #pragma unroll
        for (int g = 0; g < 8; ++g)
            s += P[(g * BM + row) * 128 + col];
        X2[row * 128 + col] = s > 0.f ? s : 0.f;
    }
    __syncthreads();

    // ---- layer 3: 16 outputs ----
    if (tid < BM * 2) {
        const int r = tid >> 1;
        const int c = tid & 1;
        float sacc = 0.f;
        #pragma unroll 8
        for (int k = 0; k < 128; ++k)
            sacc = fmaf(X2[r * 128 + k], W3[k * 2 + c], sacc);
        out[(row0 + r) * 2 + c] = sacc + b3[c];
    }
}

extern "C" void kernel_launch(void* const* d_in, const int* in_sizes, int n_in,
                              void* d_out, int out_size, void* d_ws, size_t ws_size,
                              hipStream_t stream) {
    const float* hidden = (const float*)d_in[0];
    const int*   seg    = (const int*)d_in[1];
    const float* W1     = (const float*)d_in[2];
    const float* b1     = (const float*)d_in[3];
    const float* W2     = (const float*)d_in[4];
    const float* b2     = (const float*)d_in[5];
    const float* W3     = (const float*)d_in[6];
    const float* b3     = (const float*)d_in[7];
    float* out  = (float*)d_out;
    float* sent = (float*)d_ws;  // BATCH*SMAX*DIM floats = 6 MB

    segsum_kernel<<<dim3(SMAX, BATCH), 192, 0, stream>>>(hidden, seg, sent);
    mlp_kernel<<<(BATCH * SMAX) / BM, 1024, 0, stream>>>(sent, W1, b1, W2, b2, W3, b3, out);
}